// Round 15
// baseline (838.555 us; speedup 1.0000x reference)
//
#include <hip/hip_runtime.h>
#include <hip/hip_bf16.h>

typedef __attribute__((ext_vector_type(8))) short short8;
typedef __attribute__((ext_vector_type(4))) float floatx4;

#define IN_DIM  4096
#define OUT_DIM 4096
#define MROWS   16384
#define GSIZE   128

template <int N> struct IC { static constexpr int value = N; };

__device__ __forceinline__ unsigned short f2bf(float f) {
    unsigned int u = __builtin_bit_cast(unsigned int, f);
    u = (u + 0x7fffu + ((u >> 16) & 1u)) >> 16;
    return (unsigned short)u;
}

#define GLD16(gsrc, ldst)                                                     \
    __builtin_amdgcn_global_load_lds(                                         \
        (const __attribute__((address_space(1))) unsigned int*)(const void*)(gsrc), \
        (__attribute__((address_space(3))) unsigned int*)(void*)(ldst),       \
        16, 0, 0)

// ---------------------------------------------------------------- convert x
__global__ void convert_x(const float* __restrict__ x,
                          unsigned short* __restrict__ xb, int n8) {
    int stride = gridDim.x * blockDim.x;
    for (int i = blockIdx.x * blockDim.x + threadIdx.x; i < n8; i += stride) {
        const float4* xf = (const float4*)x;
        float4 f0 = xf[2 * i];
        float4 f1 = xf[2 * i + 1];
        union { unsigned short u[8]; uint4 v; } pk;
        pk.u[0] = f2bf(f0.x); pk.u[1] = f2bf(f0.y);
        pk.u[2] = f2bf(f0.z); pk.u[3] = f2bf(f0.w);
        pk.u[4] = f2bf(f1.x); pk.u[5] = f2bf(f1.y);
        pk.u[6] = f2bf(f1.z); pk.u[7] = f2bf(f1.w);
        ((uint4*)xb)[i] = pk.v;
    }
}

// ---------------------------------------------------------------- decode W
__global__ void decode_w(const int* __restrict__ pw,
                         const float* __restrict__ norms,
                         const float* __restrict__ s1,
                         const float* __restrict__ s2,
                         const float* __restrict__ cent,
                         unsigned short* __restrict__ W) {
    int row  = blockIdx.x * 4 + (threadIdx.x >> 6);
    int lane = threadIdx.x & 63;
    float nrm = norms[row];
    int c0 = pw[(size_t)row * GSIZE + lane];
    int c1 = pw[(size_t)row * GSIZE + lane + 64];
    float e0 = cent[c0] * nrm * s2[lane];
    float e1 = cent[c1] * nrm * s2[lane + 64];
#pragma unroll
    for (int it = 0; it < 7; ++it) {
        float a = e0, b = e1;
        e0 = a + b;
        e1 = a - b;
    }
    const float inv = 0.08838834764831845f; // 1/sqrt(128)
    int o = row >> 5, g = row & 31;
    unsigned short* wr = W + (size_t)o * IN_DIM + g * GSIZE;
    wr[lane]      = f2bf(e0 * inv * s1[lane]);
    wr[lane + 64] = f2bf(e1 * inv * s1[lane + 64]);
}

// ---------------------------------------------------------------- GEMM
// 256x256 tile, BK=64, 8 waves (2M x 4N), 16x16x32 MFMA. COUNTED-LGKM
// one-phase-ahead pipeline: phase p issues a SMALL read batch needed at
// p+1, then waits lgkmcnt(batch) -- certifying all OLDER reads (operands
// + WAR) while the new batch drains UNDER this phase's MFMA. No lgkm(0)
// in the steady loop.
//
// Quadrants (16 MFMA, full K=64): Q0=aL*bL, Q1=aL*bH, Q2=aH*bL, Q3=aH*bH.
// Phase skeleton (tile j, BF=j&1, OF=BF^1):
//  P0: LD bH(j)[4];        STG A0(j+2)->BF; lgkm(4); BAR; MFMA Q0
//  P1: LD aH(j)[8];        STG B0(j+2)->BF; vmcnt(4); lgkm(8); BAR; MFMA Q1
//  P2: LD aL(j+1)[8 OF];   STG B1(j+2)->BF; lgkm(8); BAR; MFMA Q2
//  P3: LD bL(j+1)[4 OF];   STG A1(j+2)->BF; lgkm(4); BAR; MFMA Q3
//
// Ledger: every MFMA operand read >=1 phase old -> compiler emits cold
// counted waits. Stage targets' reads are >=2 phases old, certified by the
// pre-bar lgkm(N) (per-wave DS FIFO: <=N outstanding => all older done)
// and globalized by the BAR. vmcnt(4)@P1 leaves only P0+P1 stages -> tile
// j+1 (staged during tile j-1) fully landed before first read at P2.
__global__ __launch_bounds__(512, 2)
void gemm_bf16(const unsigned short* __restrict__ Xg,
               const unsigned short* __restrict__ Wg,
               const float* __restrict__ bias,
               float* __restrict__ out) {
    __shared__ unsigned short As[2][256][64];
    __shared__ unsigned short Bs[2][256][64];

    // bijective XCD swizzle (1024 blocks % 8 == 0); consecutive ids share mt
    int id = (blockIdx.x & 7) * 128 + (blockIdx.x >> 3);
    int mt = id >> 4, nt = id & 15;
    int m0 = mt * 256, n0 = nt * 256;

    int tid  = threadIdx.x;
    int lane = tid & 63;
    int wid  = tid >> 6;
    int wm = wid >> 2, wn = wid & 3;   // wave tile: rows wm*128+, cols wn*64+

    int sr0 = tid >> 3;        // 0..63
    int cp0 = tid & 7;         // physical 16B-chunk position
    int sg0 = cp0 ^ (sr0 & 7); // global chunk (inverse swizzle)

// A region h: h=0 -> rows [0,64)u[128,192) (m-frags 0-3 of both wm);
//             h=1 -> rows [64,128)u[192,256) (m-frags 4-7)
#define STG_AH(bufc, h, j) do {                                               \
    const unsigned short* _s =                                                \
        Xg + (size_t)(m0 + (h)*64 + sr0) * IN_DIM + (size_t)(j)*64 + sg0*8;   \
    GLD16(_s,                 &As[bufc][(h)*64 + sr0][cp0 * 8]);              \
    GLD16(_s + 128 * IN_DIM,  &As[bufc][128 + (h)*64 + sr0][cp0 * 8]);        \
  } while (0)
// B region h: 32-row stripes (r>>5)&1 == h -> n-frags {0,1} / {2,3} of
// every wn. Rows br = (sr0&31) + 64*(sr0>>5) + 32h, and br+128.
#define STG_BH(bufc, h, j) do {                                               \
    int _br = (sr0 & 31) + ((sr0 >> 5) << 6) + (h)*32;                        \
    const unsigned short* _s =                                                \
        Wg + (size_t)(n0 + _br) * IN_DIM + (size_t)(j)*64 + sg0*8;            \
    GLD16(_s,                 &Bs[bufc][_br][cp0 * 8]);                       \
    GLD16(_s + 128 * IN_DIM,  &Bs[bufc][_br + 128][cp0 * 8]);                 \
  } while (0)

    int rl = lane & 15, kc = lane >> 4;
    short8 aL[4][2], aH[4][2], bL[2][2], bH[2][2];
    floatx4 acc[8][4] = {};

#define RD_A(BFc, m, ks)                                                      \
    (*(const short8*)&As[BFc][wm*128 + (m)*16 + rl]                           \
         [((((ks)*4 + kc) ^ (rl & 7)) << 3)])
#define RD_B(BFc, n, ks)                                                      \
    (*(const short8*)&Bs[BFc][wn*64 + (n)*16 + rl]                            \
         [((((ks)*4 + kc) ^ (rl & 7)) << 3)])

#define LD_AL(BFc) do { _Pragma("unroll") for (int m = 0; m < 4; ++m)         \
    { aL[m][0] = RD_A(BFc, m, 0); aL[m][1] = RD_A(BFc, m, 1); } } while (0)
#define LD_AH(BFc) do { _Pragma("unroll") for (int m = 0; m < 4; ++m)         \
    { aH[m][0] = RD_A(BFc, m + 4, 0); aH[m][1] = RD_A(BFc, m + 4, 1); } } while (0)
#define LD_BL(BFc) do { _Pragma("unroll") for (int n = 0; n < 2; ++n)         \
    { bL[n][0] = RD_B(BFc, n, 0); bL[n][1] = RD_B(BFc, n, 1); } } while (0)
#define LD_BH(BFc) do { _Pragma("unroll") for (int n = 0; n < 2; ++n)         \
    { bH[n][0] = RD_B(BFc, n + 2, 0); bH[n][1] = RD_B(BFc, n + 2, 1); } } while (0)

#define MFMA_Q(AF, BG, MO, NO) do {                                           \
    __builtin_amdgcn_s_setprio(1);                                            \
    _Pragma("unroll") for (int ks = 0; ks < 2; ++ks) {                        \
      _Pragma("unroll") for (int m = 0; m < 4; ++m) {                         \
        _Pragma("unroll") for (int n = 0; n < 2; ++n)                         \
          acc[m + (MO)][n + (NO)] = __builtin_amdgcn_mfma_f32_16x16x32_bf16(  \
              AF[m][ks], BG[n][ks], acc[m + (MO)][n + (NO)], 0, 0, 0);        \
      }                                                                       \
    }                                                                         \
    __builtin_amdgcn_s_setprio(0);                                            \
  } while (0)

#define LGKM(N)  asm volatile("s_waitcnt lgkmcnt(" #N ")" ::: "memory")
#define VMC(N)   asm volatile("s_waitcnt vmcnt(" #N ")" ::: "memory")
#define BAR()    __builtin_amdgcn_s_barrier()

    // ---- prologue: tile0 -> buf0, tile1 -> buf1 (16 VMEM); certify tile0;
    //      preload aL(0), bL(0)
    STG_AH(0, 0, 0); STG_BH(0, 0, 0); STG_BH(0, 1, 0); STG_AH(0, 1, 0);
    STG_AH(1, 0, 1); STG_BH(1, 0, 1); STG_BH(1, 1, 1); STG_AH(1, 1, 1);
    VMC(8);                       // tile0 resident (8 newest = tile1)
    BAR();
    LD_AL(0); LD_BL(0);

    // MODE: 2 steady; 1 = j=62 (no stages, vmcnt(0)@P1); 0 = j=63 (tail)
    auto body = [&](int j, auto bfc, auto modec) {
        constexpr int BF   = decltype(bfc)::value;
        constexpr int MODE = decltype(modec)::value;
        constexpr int OF   = BF ^ 1;
        // ---- P0: bH(j); stage A0(j+2)
        LD_BH(BF);
        if constexpr (MODE == 2) STG_AH(BF, 0, j + 2);
        LGKM(4);
        BAR();
        MFMA_Q(aL, bL, 0, 0);                        // Q0
        // ---- P1: aH(j); stage B0(j+2); vmcnt -> tile j+1 resident
        LD_AH(BF);
        if constexpr (MODE == 2) { STG_BH(BF, 0, j + 2); VMC(4); }
        else if constexpr (MODE == 1) VMC(0);
        LGKM(8);
        BAR();
        MFMA_Q(aL, bH, 0, 2);                        // Q1 (last aL use)
        // ---- P2: aL(j+1) from OF; stage B1(j+2)
        if constexpr (MODE >= 1) LD_AL(OF);
        if constexpr (MODE == 2) STG_BH(BF, 1, j + 2);
        if constexpr (MODE >= 1) LGKM(8); else LGKM(0);
        BAR();
        MFMA_Q(aH, bL, 4, 0);                        // Q2 (last bL use)
        // ---- P3: bL(j+1) from OF; stage A1(j+2)
        if constexpr (MODE >= 1) LD_BL(OF);
        if constexpr (MODE == 2) STG_AH(BF, 1, j + 2);
        if constexpr (MODE >= 1) LGKM(4); else LGKM(0);
        BAR();
        MFMA_Q(aH, bH, 4, 2);                        // Q3
    };

    for (int j = 0; j < 62; j += 2) {
        body(j,     IC<0>{}, IC<2>{});
        body(j + 1, IC<1>{}, IC<2>{});
    }
    body(62, IC<0>{}, IC<1>{});
    body(63, IC<1>{}, IC<0>{});

    // ---- epilogue: C/D layout col = lane&15, row = (lane>>4)*4 + i
    int q = lane >> 4;
#pragma unroll
    for (int n = 0; n < 4; ++n) {
        int col = n0 + wn * 64 + n * 16 + rl;
        float bv = bias[col];
#pragma unroll
        for (int m = 0; m < 8; ++m) {
#pragma unroll
            for (int i = 0; i < 4; ++i) {
                int row = m0 + wm * 128 + m * 16 + q * 4 + i;
                out[(size_t)row * OUT_DIM + col] = acc[m][n][i] + bv;
            }
        }
    }
#undef STG_AH
#undef STG_BH
#undef RD_A
#undef RD_B
#undef LD_AL
#undef LD_AH
#undef LD_BL
#undef LD_BH
#undef MFMA_Q
#undef LGKM
#undef VMC
#undef BAR
}

// ---------------------------------------------------------------- launch
extern "C" void kernel_launch(void* const* d_in, const int* in_sizes, int n_in,
                              void* d_out, int out_size, void* d_ws, size_t ws_size,
                              hipStream_t stream) {
    const float* x     = (const float*)d_in[0];
    const int*   pw    = (const int*)d_in[1];
    const float* norms = (const float*)d_in[2];
    const float* s1    = (const float*)d_in[3];
    const float* s2    = (const float*)d_in[4];
    const float* cent  = (const float*)d_in[5];
    const float* bias  = (const float*)d_in[6];
    float* out = (float*)d_out;

    size_t needX = (size_t)MROWS * IN_DIM * 2;    // 128 MB
    size_t needW = (size_t)OUT_DIM * IN_DIM * 2;  //  32 MB
    if (ws_size < needX + needW) return;

    unsigned short* Xb = (unsigned short*)d_ws;
    unsigned short* Wb = (unsigned short*)((char*)d_ws + needX);

    convert_x<<<2048, 256, 0, stream>>>(x, Xb, MROWS * IN_DIM / 8);
    decode_w<<<(OUT_DIM * 32) / 4, 256, 0, stream>>>(pw, norms, s1, s2, cent, Wb);
    gemm_bf16<<<(MROWS / 256) * (OUT_DIM / 256), 512, 0, stream>>>(Xb, Wb, bias, out);
}

// Round 16
// 484.074 us; speedup vs baseline: 1.7323x; 1.7323x over previous
//
#include <hip/hip_runtime.h>
#include <hip/hip_bf16.h>

typedef __attribute__((ext_vector_type(4))) int   intx4;
typedef __attribute__((ext_vector_type(8))) short short8;

#define IN_DIM  4096
#define OUT_DIM 4096
#define MROWS   16384
#define GSIZE   128

template <int N> struct IC { static constexpr int value = N; };

__device__ __forceinline__ unsigned short f2bf(float f) {
    unsigned int u = __builtin_bit_cast(unsigned int, f);
    u = (u + 0x7fffu + ((u >> 16) & 1u)) >> 16;
    return (unsigned short)u;
}

__device__ __forceinline__ int q8(float v, float inv) {
    float q = rintf(v * inv);
    q = fmaxf(-127.f, fminf(127.f, q));
    return (int)q & 0xff;
}

#define GLD16(gsrc, ldst)                                                     \
    __builtin_amdgcn_global_load_lds(                                         \
        (const __attribute__((address_space(1))) unsigned int*)(const void*)(gsrc), \
        (__attribute__((address_space(3))) unsigned int*)(void*)(ldst),       \
        16, 0, 0)

// ------------------------------------------------- convert x -> i8 per-row
__global__ void convert_x_i8(const float* __restrict__ x,
                             signed char* __restrict__ xq,
                             float* __restrict__ sx) {
    int row = blockIdx.x;
    int tid = threadIdx.x;                  // 256 threads, 16 elems each
    const float4* xr = (const float4*)(x + (size_t)row * IN_DIM);
    float v[16];
    float mx = 0.f;
#pragma unroll
    for (int k = 0; k < 4; ++k) {
        float4 f = xr[tid * 4 + k];
        v[4 * k + 0] = f.x; v[4 * k + 1] = f.y;
        v[4 * k + 2] = f.z; v[4 * k + 3] = f.w;
        mx = fmaxf(mx, fmaxf(fmaxf(fabsf(f.x), fabsf(f.y)),
                             fmaxf(fabsf(f.z), fabsf(f.w))));
    }
#pragma unroll
    for (int off = 32; off; off >>= 1) mx = fmaxf(mx, __shfl_xor(mx, off));
    __shared__ float wm[4];
    if ((tid & 63) == 0) wm[tid >> 6] = mx;
    __syncthreads();
    float bmax = fmaxf(fmaxf(wm[0], wm[1]), fmaxf(wm[2], wm[3]));
    float inv = bmax > 0.f ? 127.f / bmax : 0.f;
    if (tid == 0) sx[row] = bmax > 0.f ? bmax / 127.f : 0.f;
    int p[4];
#pragma unroll
    for (int k = 0; k < 4; ++k)
        p[k] = q8(v[4*k], inv) | (q8(v[4*k+1], inv) << 8) |
               (q8(v[4*k+2], inv) << 16) | (q8(v[4*k+3], inv) << 24);
    ((int4*)(xq + (size_t)row * IN_DIM))[tid] = make_int4(p[0], p[1], p[2], p[3]);
}

// ---------------------------------------------------------------- decode W
__global__ void decode_w(const int* __restrict__ pw,
                         const float* __restrict__ norms,
                         const float* __restrict__ s1,
                         const float* __restrict__ s2,
                         const float* __restrict__ cent,
                         unsigned short* __restrict__ W) {
    int row  = blockIdx.x * 4 + (threadIdx.x >> 6);
    int lane = threadIdx.x & 63;
    float nrm = norms[row];
    int c0 = pw[(size_t)row * GSIZE + lane];
    int c1 = pw[(size_t)row * GSIZE + lane + 64];
    float e0 = cent[c0] * nrm * s2[lane];
    float e1 = cent[c1] * nrm * s2[lane + 64];
#pragma unroll
    for (int it = 0; it < 7; ++it) {
        float a = e0, b = e1;
        e0 = a + b;
        e1 = a - b;
    }
    const float inv = 0.08838834764831845f; // 1/sqrt(128)
    int o = row >> 5, g = row & 31;
    unsigned short* wr = W + (size_t)o * IN_DIM + g * GSIZE;
    wr[lane]      = f2bf(e0 * inv * s1[lane]);
    wr[lane + 64] = f2bf(e1 * inv * s1[lane + 64]);
}

// ------------------------------------------------- quantize W -> i8 per-row
__global__ void quant_w(const unsigned short* __restrict__ Wb,
                        signed char* __restrict__ wq,
                        float* __restrict__ sw) {
    int o = blockIdx.x;
    int tid = threadIdx.x;                  // 256 threads, 16 elems each
    const uint4* wr = (const uint4*)(Wb + (size_t)o * IN_DIM);
    float v[16];
    float mx = 0.f;
#pragma unroll
    for (int k = 0; k < 2; ++k) {
        uint4 u = wr[tid * 2 + k];
        unsigned int ws[4] = {u.x, u.y, u.z, u.w};
#pragma unroll
        for (int d = 0; d < 4; ++d) {
            float lo = __builtin_bit_cast(float, (ws[d] & 0xffffu) << 16);
            float hi = __builtin_bit_cast(float, (ws[d] & 0xffff0000u));
            v[8 * k + 2 * d]     = lo;
            v[8 * k + 2 * d + 1] = hi;
            mx = fmaxf(mx, fmaxf(fabsf(lo), fabsf(hi)));
        }
    }
#pragma unroll
    for (int off = 32; off; off >>= 1) mx = fmaxf(mx, __shfl_xor(mx, off));
    __shared__ float wm[4];
    if ((tid & 63) == 0) wm[tid >> 6] = mx;
    __syncthreads();
    float bmax = fmaxf(fmaxf(wm[0], wm[1]), fmaxf(wm[2], wm[3]));
    float inv = bmax > 0.f ? 127.f / bmax : 0.f;
    if (tid == 0) sw[o] = bmax > 0.f ? bmax / 127.f : 0.f;
    int p[4];
#pragma unroll
    for (int k = 0; k < 4; ++k)
        p[k] = q8(v[4*k], inv) | (q8(v[4*k+1], inv) << 8) |
               (q8(v[4*k+2], inv) << 16) | (q8(v[4*k+3], inv) << 24);
    ((int4*)(wq + (size_t)o * IN_DIM))[tid] = make_int4(p[0], p[1], p[2], p[3]);
}

// ---------------------------------------------------------------- GEMM i8
// R14's proven skeleton, i8 16x16x64 MFMA (K=64/inst): per tile 32 MFMA +
// 12 ds_read_b128 per wave (half the bf16 LDS bytes). 256x256 tile, BK=64,
// 8 waves (2M x 4N). 2 phases/tile, hot lgkm on small batches, counted
// vmcnt(3). LDS 64 KiB total. Chunk swizzle: phys = c ^ (r&3) ^ ((r>>2)&3)
// (uniform 2-way bank aliasing = free, m136).
//
// Per tile j (BF=j&1):
//  p0: LD B n0-3 + A m0-3 (8 reads); stage A1(j+1)->BF^1; lgkm0;
//      MFMA m0-3 x n0-3 (16); BAR
//  p1: LD A m4-7 (4 reads); stage A0,B0,B1(j+2)->BF; lgkm0;
//      MFMA m4-7 x n0-3 (16); vmcnt(3); BAR
// WAR: p1 stage targets (A0,B0,B1 of BF) read at p0, certified by p0's
// lgkm0+BAR. A1(BF) read p1, staged next phase (p0(j+1)) after p1's BAR.
// RAW: vmcnt(3) leaves only this-phase stages -> tile j+1 landed; BAR
// globalizes before p0(j+1) reads.
__global__ __launch_bounds__(512, 2)
void gemm_i8(const signed char* __restrict__ Xq,
             const signed char* __restrict__ Wq,
             const float* __restrict__ sx,
             const float* __restrict__ sw,
             const float* __restrict__ bias,
             float* __restrict__ out) {
    __shared__ signed char As[2][256][64];
    __shared__ signed char Bs[2][256][64];

    // bijective XCD swizzle (1024 blocks % 8 == 0); consecutive ids share mt
    int id = (blockIdx.x & 7) * 128 + (blockIdx.x >> 3);
    int mt = id >> 4, nt = id & 15;
    int m0 = mt * 256, n0 = nt * 256;

    int tid  = threadIdx.x;
    int lane = tid & 63;
    int wid  = tid >> 6;
    int wm = wid >> 2, wn = wid & 3;   // wave tile: rows wm*128+, cols wn*64+

    // staging: 512 chunks of 16B per 128-row half; 1 GLD/thread/half
    int sr = tid >> 2;                          // 0..127
    int cp = tid & 3;                           // physical chunk
    int sg = cp ^ (sr & 3) ^ ((sr >> 2) & 3);   // global chunk (involution)

// A half h: rows (sr&63) + (sr>>6)*128 + h*64  (h=0 -> m0-3 rows, h=1 -> m4-7)
#define STG_AH(bufc, h, j) do {                                               \
    int _r = (sr & 63) + ((sr >> 6) << 7) + (h)*64;                           \
    GLD16(Xq + (size_t)(m0 + _r) * IN_DIM + (size_t)(j)*64 + sg*16,           \
          &As[bufc][_r][cp * 16]);                                            \
  } while (0)
// B half h: rows h*128 + sr
#define STG_BH(bufc, h, j) do {                                               \
    int _r = (h)*128 + sr;                                                    \
    GLD16(Wq + (size_t)(n0 + _r) * IN_DIM + (size_t)(j)*64 + sg*16,           \
          &Bs[bufc][_r][cp * 16]);                                            \
  } while (0)

    int rl = lane & 15, kc = lane >> 4;
    int rsw = (kc ^ (rl & 3) ^ ((rl >> 2) & 3)) << 4;  // read chunk byte-off
    intx4 a_[8], b_[4];
    intx4 acc[8][4] = {};

#define LD_A(BFc, m)                                                          \
    a_[m] = *(const intx4*)&As[BFc][wm*128 + (m)*16 + rl][rsw]
#define LD_B(BFc, n)                                                          \
    b_[n] = *(const intx4*)&Bs[BFc][wn*64 + (n)*16 + rl][rsw]

#define LGKM0() asm volatile("s_waitcnt lgkmcnt(0)" ::: "memory")
#define BAR()   __builtin_amdgcn_s_barrier()

#define MFMA_H(mh) do {                                                       \
    __builtin_amdgcn_s_setprio(1);                                            \
    _Pragma("unroll") for (int m = 4*(mh); m < 4*(mh) + 4; ++m) {             \
      _Pragma("unroll") for (int n = 0; n < 4; ++n)                           \
        acc[m][n] = __builtin_amdgcn_mfma_i32_16x16x64_i8(                    \
            a_[m], b_[n], acc[m][n], 0, 0, 0);                                \
    }                                                                         \
    __builtin_amdgcn_s_setprio(0);                                            \
  } while (0)

    // ---- prologue: tile0 all 4 halves; tile1 A0,B0,B1 (7 GLD total)
    STG_AH(0, 0, 0); STG_AH(0, 1, 0); STG_BH(0, 0, 0); STG_BH(0, 1, 0);
    STG_AH(1, 0, 1); STG_BH(1, 0, 1); STG_BH(1, 1, 1);
    asm volatile("s_waitcnt vmcnt(3)" ::: "memory");  // tile0 resident
    BAR();

    // MODE: 2 = steady; 1 = j=62 (p0 stage A1(63); p1 no stage, vmcnt(0));
    //       0 = j=63 tail
    auto body = [&](int j, auto bfc, auto modec) {
        constexpr int BF   = decltype(bfc)::value;
        constexpr int MODE = decltype(modec)::value;
        // ---- p0
        LD_B(BF, 0); LD_B(BF, 1); LD_B(BF, 2); LD_B(BF, 3);
        LD_A(BF, 0); LD_A(BF, 1); LD_A(BF, 2); LD_A(BF, 3);
        if constexpr (MODE >= 1) STG_AH(BF ^ 1, 1, j + 1);
        LGKM0();
        MFMA_H(0);
        BAR();
        // ---- p1
        LD_A(BF, 4); LD_A(BF, 5); LD_A(BF, 6); LD_A(BF, 7);
        if constexpr (MODE == 2) {
            STG_AH(BF, 0, j + 2); STG_BH(BF, 0, j + 2); STG_BH(BF, 1, j + 2);
        }
        LGKM0();
        MFMA_H(1);
        if constexpr (MODE == 2)
            asm volatile("s_waitcnt vmcnt(3)" ::: "memory"); // tile j+1 landed
        else if constexpr (MODE == 1)
            asm volatile("s_waitcnt vmcnt(0)" ::: "memory");
        if constexpr (MODE >= 1) BAR();
    };

    for (int j = 0; j < 62; j += 2) {
        body(j,     IC<0>{}, IC<2>{});
        body(j + 1, IC<1>{}, IC<2>{});
    }
    body(62, IC<0>{}, IC<1>{});
    body(63, IC<1>{}, IC<0>{});

    // ---- epilogue: C/D col = lane&15, row = (lane>>4)*4 + i (shape-det.)
    int q = lane >> 4;
    float sxv[8][4];
#pragma unroll
    for (int m = 0; m < 8; ++m)
#pragma unroll
        for (int i = 0; i < 4; ++i)
            sxv[m][i] = sx[m0 + wm * 128 + m * 16 + q * 4 + i];
#pragma unroll
    for (int n = 0; n < 4; ++n) {
        int col = n0 + wn * 64 + n * 16 + rl;
        float swc = sw[col];
        float bv  = bias[col];
#pragma unroll
        for (int m = 0; m < 8; ++m) {
#pragma unroll
            for (int i = 0; i < 4; ++i) {
                int row = m0 + wm * 128 + m * 16 + q * 4 + i;
                out[(size_t)row * OUT_DIM + col] =
                    (float)acc[m][n][i] * (sxv[m][i] * swc) + bv;
            }
        }
    }
#undef STG_AH
#undef STG_BH
#undef LD_A
#undef LD_B
#undef LGKM0
#undef BAR
#undef MFMA_H
}

// ---------------------------------------------------------------- launch
extern "C" void kernel_launch(void* const* d_in, const int* in_sizes, int n_in,
                              void* d_out, int out_size, void* d_ws, size_t ws_size,
                              hipStream_t stream) {
    const float* x     = (const float*)d_in[0];
    const int*   pw    = (const int*)d_in[1];
    const float* norms = (const float*)d_in[2];
    const float* s1    = (const float*)d_in[3];
    const float* s2    = (const float*)d_in[4];
    const float* cent  = (const float*)d_in[5];
    const float* bias  = (const float*)d_in[6];
    float* out = (float*)d_out;

    size_t offXq = 0;                                  // 64 MB i8 X
    size_t offWb = offXq + (size_t)MROWS * IN_DIM;     // 32 MB bf16 W
    size_t offWq = offWb + (size_t)OUT_DIM * IN_DIM * 2;  // 16 MB i8 W
    size_t offSx = offWq + (size_t)OUT_DIM * IN_DIM;   // 64 KB
    size_t offSw = offSx + (size_t)MROWS * 4;          // 16 KB
    size_t need  = offSw + (size_t)OUT_DIM * 4;
    if (ws_size < need) return;

    signed char*    Xq = (signed char*)d_ws + offXq;
    unsigned short* Wb = (unsigned short*)((char*)d_ws + offWb);
    signed char*    Wq = (signed char*)d_ws + offWq;
    float*          sx = (float*)((char*)d_ws + offSx);
    float*          sw = (float*)((char*)d_ws + offSw);

    convert_x_i8<<<MROWS, 256, 0, stream>>>(x, Xq, sx);
    decode_w<<<(OUT_DIM * 32) / 4, 256, 0, stream>>>(pw, norms, s1, s2, cent, Wb);
    quant_w<<<OUT_DIM, 256, 0, stream>>>(Wb, Wq, sw);
    gemm_i8<<<(MROWS / 256) * (OUT_DIM / 256), 512, 0, stream>>>(Xq, Wq, sx, sw,
                                                                 bias, out);
}

// Round 17
// 407.370 us; speedup vs baseline: 2.0585x; 1.1883x over previous
//
#include <hip/hip_runtime.h>
#include <hip/hip_bf16.h>

typedef __attribute__((ext_vector_type(4))) int intx4;

#define IN_DIM  4096
#define OUT_DIM 4096
#define MROWS   16384
#define GSIZE   128

template <int N> struct IC { static constexpr int value = N; };

__device__ __forceinline__ int q8(float v, float inv) {
    float q = rintf(v * inv);
    q = fmaxf(-127.f, fminf(127.f, q));
    return (int)q & 0xff;
}

#define GLD16(gsrc, ldst)                                                     \
    __builtin_amdgcn_global_load_lds(                                         \
        (const __attribute__((address_space(1))) unsigned int*)(const void*)(gsrc), \
        (__attribute__((address_space(3))) unsigned int*)(void*)(ldst),       \
        16, 0, 0)

// ------------------------------------------------- convert x -> i8 per-row
__global__ void convert_x_i8(const float* __restrict__ x,
                             signed char* __restrict__ xq,
                             float* __restrict__ sx) {
    int row = blockIdx.x;
    int tid = threadIdx.x;                  // 256 threads, 16 elems each
    const float4* xr = (const float4*)(x + (size_t)row * IN_DIM);
    float v[16];
    float mx = 0.f;
#pragma unroll
    for (int k = 0; k < 4; ++k) {
        float4 f = xr[tid * 4 + k];
        v[4 * k + 0] = f.x; v[4 * k + 1] = f.y;
        v[4 * k + 2] = f.z; v[4 * k + 3] = f.w;
        mx = fmaxf(mx, fmaxf(fmaxf(fabsf(f.x), fabsf(f.y)),
                             fmaxf(fabsf(f.z), fabsf(f.w))));
    }
#pragma unroll
    for (int off = 32; off; off >>= 1) mx = fmaxf(mx, __shfl_xor(mx, off));
    __shared__ float wm[4];
    if ((tid & 63) == 0) wm[tid >> 6] = mx;
    __syncthreads();
    float bmax = fmaxf(fmaxf(wm[0], wm[1]), fmaxf(wm[2], wm[3]));
    float inv = bmax > 0.f ? 127.f / bmax : 0.f;
    if (tid == 0) sx[row] = bmax > 0.f ? bmax / 127.f : 0.f;
    int p[4];
#pragma unroll
    for (int k = 0; k < 4; ++k)
        p[k] = q8(v[4*k], inv) | (q8(v[4*k+1], inv) << 8) |
               (q8(v[4*k+2], inv) << 16) | (q8(v[4*k+3], inv) << 24);
    ((int4*)(xq + (size_t)row * IN_DIM))[tid] = make_int4(p[0], p[1], p[2], p[3]);
}

// --------------------------------------- fused decode + quantize W -> i8
// One block (256 thr) per output row o: 32 groups x 8 threads; thread
// handles 8 element-pairs (i, i+64) of its group (WHT is pairwise), then
// block max -> per-row scale -> quantize -> write i8. No bf16 round-trip.
__global__ void decode_quant_w(const int* __restrict__ pw,
                               const float* __restrict__ norms,
                               const float* __restrict__ s1,
                               const float* __restrict__ s2,
                               const float* __restrict__ cent,
                               signed char* __restrict__ wq,
                               float* __restrict__ sw) {
    int o   = blockIdx.x;
    int tid = threadIdx.x;
    int g   = tid >> 3;        // group 0..31
    int k   = tid & 7;         // sub-slot: elems [k*8, k*8+8) and +64
    const int* pr = pw + ((size_t)o * 32 + g) * GSIZE;
    float nrm = norms[o * 32 + g];
    const float inv = 0.08838834764831845f; // 1/sqrt(128)

    float v0[8], v1[8];
    float mx = 0.f;
#pragma unroll
    for (int i = 0; i < 8; ++i) {
        int idx = k * 8 + i;
        float e0 = cent[pr[idx]]      * nrm * s2[idx];
        float e1 = cent[pr[idx + 64]] * nrm * s2[idx + 64];
#pragma unroll
        for (int it = 0; it < 7; ++it) {
            float a = e0, b = e1;
            e0 = a + b;
            e1 = a - b;
        }
        v0[i] = e0 * inv * s1[idx];
        v1[i] = e1 * inv * s1[idx + 64];
        mx = fmaxf(mx, fmaxf(fabsf(v0[i]), fabsf(v1[i])));
    }
#pragma unroll
    for (int off = 32; off; off >>= 1) mx = fmaxf(mx, __shfl_xor(mx, off));
    __shared__ float wm[4];
    if ((tid & 63) == 0) wm[tid >> 6] = mx;
    __syncthreads();
    float bmax = fmaxf(fmaxf(wm[0], wm[1]), fmaxf(wm[2], wm[3]));
    float qinv = bmax > 0.f ? 127.f / bmax : 0.f;
    if (tid == 0) sw[o] = bmax > 0.f ? bmax / 127.f : 0.f;

    int p0 = q8(v0[0],qinv) | (q8(v0[1],qinv)<<8) | (q8(v0[2],qinv)<<16) | (q8(v0[3],qinv)<<24);
    int p1 = q8(v0[4],qinv) | (q8(v0[5],qinv)<<8) | (q8(v0[6],qinv)<<16) | (q8(v0[7],qinv)<<24);
    int p2 = q8(v1[0],qinv) | (q8(v1[1],qinv)<<8) | (q8(v1[2],qinv)<<16) | (q8(v1[3],qinv)<<24);
    int p3 = q8(v1[4],qinv) | (q8(v1[5],qinv)<<8) | (q8(v1[6],qinv)<<16) | (q8(v1[7],qinv)<<24);
    signed char* wr = wq + (size_t)o * IN_DIM + g * GSIZE + k * 8;
    *(int2*)wr        = make_int2(p0, p1);
    *(int2*)(wr + 64) = make_int2(p2, p3);
}

// ---------------------------------------------------------------- GEMM i8
// R14's proven schedule with i8 16x16x64 MFMA and BK=128: LDS rows are
// 128 B with 8x16B chunks and phys = c ^ (row&7) -- BYTE-IDENTICAL address
// pattern to the bf16 kernel that measured 0 bank conflicts (the 64B-row
// 4-chunk variant measured 2.5e7). 256x256 tile, 32 K-tiles, 8 waves
// (2M x 4N). Per tile per wave: 24 ds_read_b128, 64 MFMA in 4 quadrant
// phases of 16, hot lgkm, 1 barrier/phase, counted vmcnt(6).
//
// Quadrants: p0 (m0-3,n0-1) reads B n0-1 + A m0-3 (12); p1 (m0-3,n2-3)
// reads B n2-3 (4); p2 (m4-7,n0-1) reads A m4-7 (8); p3 (m4-7,n2-3) 0.
// Stage plan at tile j (BF=j&1): p0: A1(j+1)->BF^1 [read p2(j-1)];
// p1: A0(j+2)->BF [read p0]; p2: B0(j+2)->BF [read p0/p1]; p3: B1(j+2)->BF
// then vmcnt(6) leaves {A0,B0,B1}(j+2) -> tile j+1 resident; BAR globalizes.
__global__ __launch_bounds__(512, 2)
void gemm_i8(const signed char* __restrict__ Xq,
             const signed char* __restrict__ Wq,
             const float* __restrict__ sx,
             const float* __restrict__ sw,
             const float* __restrict__ bias,
             float* __restrict__ out) {
    __shared__ signed char As[2][256][128];
    __shared__ signed char Bs[2][256][128];

    // bijective XCD swizzle (1024 blocks % 8 == 0); consecutive ids share mt
    int id = (blockIdx.x & 7) * 128 + (blockIdx.x >> 3);
    int mt = id >> 4, nt = id & 15;
    int m0 = mt * 256, n0 = nt * 256;

    int tid  = threadIdx.x;
    int lane = tid & 63;
    int wid  = tid >> 6;
    int wm = wid >> 2, wn = wid & 3;   // wave tile: rows wm*128+, cols wn*64+

    // staging: thread covers 16B phys chunk cp0 of rows sr0 / sr0+64(+128)
    int sr0 = tid >> 3;        // 0..63
    int cp0 = tid & 7;         // physical chunk position
    int sg0 = cp0 ^ (sr0 & 7); // global chunk (inverse swizzle)

// A halves interleaved: h=0 -> rows [0,64)u[128,192) (m-frags 0-3),
//                       h=1 -> rows [64,128)u[192,256) (m-frags 4-7)
#define STG_AH(bufc, h, j) do {                                               \
    const signed char* _s =                                                   \
        Xq + (size_t)(m0 + (h)*64 + sr0) * IN_DIM + (size_t)(j)*128 + sg0*16; \
    GLD16(_s,                 &As[bufc][(h)*64 + sr0][cp0 * 16]);             \
    GLD16(_s + 128 * IN_DIM,  &As[bufc][128 + (h)*64 + sr0][cp0 * 16]);       \
  } while (0)
// B halves contiguous: h=0 -> rows [0,128), h=1 -> rows [128,256)
#define STG_BH(bufc, h, j) do {                                               \
    const signed char* _s =                                                   \
        Wq + (size_t)(n0 + (h)*128 + sr0) * IN_DIM + (size_t)(j)*128 + sg0*16;\
    GLD16(_s,                &Bs[bufc][(h)*128 + sr0][cp0 * 16]);             \
    GLD16(_s + 64 * IN_DIM,  &Bs[bufc][(h)*128 + sr0 + 64][cp0 * 16]);        \
  } while (0)

    int rl = lane & 15, kc = lane >> 4;
    intx4 a_[8][2], b_[4][2];
    intx4 acc[8][4] = {};

#define LD_A(BFc, m, ks) do {                                                 \
    int row_ = wm * 128 + (m)*16 + rl;                                        \
    a_[m][ks] = *(const intx4*)&As[BFc][row_][((((ks)*4 + kc) ^ (rl & 7)) << 4)]; \
  } while (0)
#define LD_B(BFc, n, ks) do {                                                 \
    int row_ = wn * 64 + (n)*16 + rl;                                         \
    b_[n][ks] = *(const intx4*)&Bs[BFc][row_][((((ks)*4 + kc) ^ (rl & 7)) << 4)]; \
  } while (0)

#define LGKM0() asm volatile("s_waitcnt lgkmcnt(0)" ::: "memory")
#define BAR()   __builtin_amdgcn_s_barrier()

#define MFMA_Q(mh, nh) do {                                                   \
    __builtin_amdgcn_s_setprio(1);                                            \
    _Pragma("unroll") for (int ks = 0; ks < 2; ++ks) {                        \
      _Pragma("unroll") for (int m = 4*(mh); m < 4*(mh) + 4; ++m) {           \
        _Pragma("unroll") for (int n = 2*(nh); n < 2*(nh) + 2; ++n)           \
          acc[m][n] = __builtin_amdgcn_mfma_i32_16x16x64_i8(                  \
              a_[m][ks], b_[n][ks], acc[m][n], 0, 0, 0);                      \
      }                                                                       \
    }                                                                         \
    __builtin_amdgcn_s_setprio(0);                                            \
  } while (0)

    // ---- prologue: tile0 full (8 GLD/thread); A0,B0,B1 of tile1 (6)
    STG_BH(0, 0, 0); STG_BH(0, 1, 0); STG_AH(0, 0, 0); STG_AH(0, 1, 0);
    STG_AH(1, 0, 1); STG_BH(1, 0, 1); STG_BH(1, 1, 1);
    asm volatile("s_waitcnt vmcnt(6)" ::: "memory");  // tile0 resident
    BAR();

    // MODE: 2 = steady; 1 = j=30 (stage A1(31) only, vmcnt(0)); 0 = j=31
    auto body = [&](int j, auto bfc, auto modec) {
        constexpr int BF   = decltype(bfc)::value;
        constexpr int MODE = decltype(modec)::value;
        // ---- p0: quadrant (m0-3, n0-1); 12 reads; stage A1(j+1)
        LD_B(BF, 0, 0); LD_B(BF, 0, 1); LD_B(BF, 1, 0); LD_B(BF, 1, 1);
        LD_A(BF, 0, 0); LD_A(BF, 0, 1); LD_A(BF, 1, 0); LD_A(BF, 1, 1);
        LD_A(BF, 2, 0); LD_A(BF, 2, 1); LD_A(BF, 3, 0); LD_A(BF, 3, 1);
        if constexpr (MODE >= 1) STG_AH(BF ^ 1, 1, j + 1);
        LGKM0();
        MFMA_Q(0, 0);
        BAR();
        // ---- p1: quadrant (m0-3, n2-3); 4 reads; stage A0(j+2)
        LD_B(BF, 2, 0); LD_B(BF, 2, 1); LD_B(BF, 3, 0); LD_B(BF, 3, 1);
        if constexpr (MODE == 2) STG_AH(BF, 0, j + 2);
        LGKM0();
        MFMA_Q(0, 1);
        BAR();
        // ---- p2: quadrant (m4-7, n0-1); 8 reads; stage B0(j+2)
        LD_A(BF, 4, 0); LD_A(BF, 4, 1); LD_A(BF, 5, 0); LD_A(BF, 5, 1);
        LD_A(BF, 6, 0); LD_A(BF, 6, 1); LD_A(BF, 7, 0); LD_A(BF, 7, 1);
        if constexpr (MODE == 2) STG_BH(BF, 0, j + 2);
        LGKM0();
        MFMA_Q(1, 0);
        BAR();
        // ---- p3: quadrant (m4-7, n2-3); 0 reads; stage B1(j+2); vmcnt
        if constexpr (MODE == 2) {
            STG_BH(BF, 1, j + 2);
            asm volatile("s_waitcnt vmcnt(6)" ::: "memory"); // tile j+1 landed
        } else if constexpr (MODE == 1) {
            asm volatile("s_waitcnt vmcnt(0)" ::: "memory");
        }
        MFMA_Q(1, 1);
        BAR();
    };

    for (int j = 0; j < 30; j += 2) {
        body(j,     IC<0>{}, IC<2>{});
        body(j + 1, IC<1>{}, IC<2>{});
    }
    body(30, IC<0>{}, IC<1>{});
    body(31, IC<1>{}, IC<0>{});

    // ---- epilogue: C/D col = lane&15, row = (lane>>4)*4 + i (shape-det.)
    int q = lane >> 4;
    float sxv[8][4];
#pragma unroll
    for (int m = 0; m < 8; ++m)
#pragma unroll
        for (int i = 0; i < 4; ++i)
            sxv[m][i] = sx[m0 + wm * 128 + m * 16 + q * 4 + i];
#pragma unroll
    for (int n = 0; n < 4; ++n) {
        int col = n0 + wn * 64 + n * 16 + rl;
        float swc = sw[col];
        float bv  = bias[col];
#pragma unroll
        for (int m = 0; m < 8; ++m) {
#pragma unroll
            for (int i = 0; i < 4; ++i) {
                int row = m0 + wm * 128 + m * 16 + q * 4 + i;
                out[(size_t)row * OUT_DIM + col] =
                    (float)acc[m][n][i] * (sxv[m][i] * swc) + bv;
            }
        }
    }
#undef STG_AH
#undef STG_BH
#undef LD_A
#undef LD_B
#undef LGKM0
#undef BAR
#undef MFMA_Q
}

// ---------------------------------------------------------------- launch
extern "C" void kernel_launch(void* const* d_in, const int* in_sizes, int n_in,
                              void* d_out, int out_size, void* d_ws, size_t ws_size,
                              hipStream_t stream) {
    const float* x     = (const float*)d_in[0];
    const int*   pw    = (const int*)d_in[1];
    const float* norms = (const float*)d_in[2];
    const float* s1    = (const float*)d_in[3];
    const float* s2    = (const float*)d_in[4];
    const float* cent  = (const float*)d_in[5];
    const float* bias  = (const float*)d_in[6];
    float* out = (float*)d_out;

    size_t offXq = 0;                                   // 64 MB i8 X
    size_t offWq = offXq + (size_t)MROWS * IN_DIM;      // 16 MB i8 W
    size_t offSx = offWq + (size_t)OUT_DIM * IN_DIM;    // 64 KB
    size_t offSw = offSx + (size_t)MROWS * 4;           // 16 KB
    size_t need  = offSw + (size_t)OUT_DIM * 4;
    if (ws_size < need) return;

    signed char* Xq = (signed char*)d_ws + offXq;
    signed char* Wq = (signed char*)d_ws + offWq;
    float*       sx = (float*)((char*)d_ws + offSx);
    float*       sw = (float*)((char*)d_ws + offSw);

    convert_x_i8<<<MROWS, 256, 0, stream>>>(x, Xq, sx);
    decode_quant_w<<<OUT_DIM, 256, 0, stream>>>(pw, norms, s1, s2, cent, Wq, sw);
    gemm_i8<<<(MROWS / 256) * (OUT_DIM / 256), 512, 0, stream>>>(Xq, Wq, sx, sw,
                                                                 bias, out);
}